// Round 3
// baseline (366.100 us; speedup 1.0000x reference)
//
#include <hip/hip_runtime.h>
#include <math.h>

constexpr int C = 1000;
constexpr int B = 65536;
constexpr float SMOOTH = 0.1f;
constexpr int WPC = 8;              // waves per class in loss kernel
constexpr int NW = C * WPC;         // 8000 active waves, padded to 8192
constexpr int NWPAD = 8192;         // loss grid = 2048 blocks * 4 waves

typedef float f4 __attribute__((ext_vector_type(4)));
#define NTLOAD(p) __builtin_nontemporal_load(p)

__device__ inline float wave_reduce_sum(float v) {
    #pragma unroll
    for (int off = 32; off > 0; off >>= 1)
        v += __shfl_xor(v, off, 64);
    return v;
}
__device__ inline void wave_reduce_sum2(float& a, float& b) {
    #pragma unroll
    for (int off = 32; off > 0; off >>= 1) {
        float ta = __shfl_xor(a, off, 64);
        float tb = __shfl_xor(b, off, 64);
        a += ta; b += tb;
    }
}
__device__ inline void wave_reduce_sum4(float& a, float& b, float& c, float& d) {
    #pragma unroll
    for (int off = 32; off > 0; off >>= 1) {
        float ta = __shfl_xor(a, off, 64);
        float tb = __shfl_xor(b, off, 64);
        float tc = __shfl_xor(c, off, 64);
        float td = __shfl_xor(d, off, 64);
        a += ta; b += tb; c += tc; d += td;
    }
}
__device__ inline float block_reduce_sum(float v, float* sm) {
    v = wave_reduce_sum(v);
    int wave = threadIdx.x >> 6, lane = threadIdx.x & 63;
    if (lane == 0) sm[wave] = v;
    __syncthreads();
    float r = (sm[0] + sm[1]) + (sm[2] + sm[3]);
    __syncthreads();
    return r;
}

// ---------------- binning: zero -> hist -> prefix -> scatter ----------------

__global__ __launch_bounds__(256) void zero_kernel(int* __restrict__ counts) {
    #pragma unroll
    for (int k = 0; k < 4; k++) {
        int idx = threadIdx.x + k * 256;
        if (idx < C) counts[idx] = 0;
    }
}

__global__ __launch_bounds__(256) void hist_kernel(const int* __restrict__ tgt,
                                                   int* __restrict__ counts) {
    __shared__ int lh[C];
    for (int idx = threadIdx.x; idx < C; idx += 256) lh[idx] = 0;
    __syncthreads();
    int base = blockIdx.x * 1024 + threadIdx.x;   // 64 blocks x 256 x 4 = 65536
    #pragma unroll
    for (int k = 0; k < 4; k++)
        atomicAdd(&lh[tgt[base + k * 256]], 1);
    __syncthreads();
    for (int idx = threadIdx.x; idx < C; idx += 256) {
        int v = lh[idx];
        if (v) atomicAdd(&counts[idx], v);
    }
}

__global__ __launch_bounds__(256) void prefix_kernel(const int* __restrict__ counts,
                                                     int* __restrict__ offs,
                                                     int* __restrict__ cursor) {
    __shared__ int ts[256];
    int tid = threadIdx.x;
    int c[4];
    int s = 0;
    #pragma unroll
    for (int k = 0; k < 4; k++) {
        int idx = tid * 4 + k;
        c[k] = (idx < C) ? counts[idx] : 0;
        s += c[k];
    }
    ts[tid] = s;
    __syncthreads();
    // Hillis-Steele inclusive scan over the 256 per-thread sums
    for (int off = 1; off < 256; off <<= 1) {
        int v = (tid >= off) ? ts[tid - off] : 0;
        __syncthreads();
        ts[tid] += v;
        __syncthreads();
    }
    int base = (tid > 0) ? ts[tid - 1] : 0;       // exclusive base for this thread
    #pragma unroll
    for (int k = 0; k < 4; k++) {
        int idx = tid * 4 + k;
        if (idx < C) { offs[idx] = base; cursor[idx] = base; }
        base += c[k];
    }
    if (tid == 255) offs[C] = ts[255];            // == B
}

__global__ __launch_bounds__(256) void scatter_kernel(const int* __restrict__ tgt,
                                                      int* __restrict__ cursor,
                                                      int* __restrict__ order) {
    int base = blockIdx.x * 1024 + threadIdx.x;
    #pragma unroll
    for (int k = 0; k < 4; k++) {
        int b = base + k * 256;
        int t = tgt[b];
        int pos = atomicAdd(&cursor[t], 1);
        order[pos] = b;
    }
}

// ---------------- smooth: one wave per class row ----------------
// e_j = exp(row_j); Z = sum e; A_j = e_j/Z; sums = (Z - e_t)/Z;
// S[t,j] = 0.1*(1 - A_j)/sums (diag = 0.9); Srow[t] = sum_j S[t,j].
__global__ __launch_bounds__(256) void smooth_kernel(
        const float* __restrict__ ca, float* __restrict__ S,
        float* __restrict__ Srow) {
    int wave = threadIdx.x >> 6, lane = threadIdx.x & 63;
    int t = blockIdx.x * 4 + wave;              // grid = 250 -> t in [0,1000)
    const f4* row = (const f4*)(ca + (size_t)t * C);
    bool lastl = lane < (250 - 192);

    f4 e[4];
    e[0] = row[lane];
    e[1] = row[lane + 64];
    e[2] = row[lane + 128];
    e[3] = lastl ? row[lane + 192]
                 : f4{-INFINITY, -INFINITY, -INFINITY, -INFINITY};

    float zl = 0.f;
    #pragma unroll
    for (int k = 0; k < 4; k++) {
        e[k].x = __expf(e[k].x);   // exp(-inf) = 0 on pad lanes
        e[k].y = __expf(e[k].y);
        e[k].z = __expf(e[k].z);
        e[k].w = __expf(e[k].w);
        zl += (e[k].x + e[k].y) + (e[k].z + e[k].w);
    }
    float z = wave_reduce_sum(zl);
    float inv_z = 1.0f / z;

    int q = t >> 2, owner = q & 63, kk = q >> 6, comp = t & 3;
    f4 av = (kk == 0) ? e[0] : (kk == 1) ? e[1] : (kk == 2) ? e[2] : e[3];
    float cand = (comp == 0) ? av.x : (comp == 1) ? av.y
               : (comp == 2) ? av.z : av.w;
    float ediag = __shfl(cand, owner, 64);

    float sums = (z - ediag) * inv_z;
    float coef = SMOOTH / sums;
    f4* Srt = (f4*)(S + (size_t)t * C);
    float srow_l = 0.f;
    #pragma unroll
    for (int k = 0; k < 3; k++) {
        int jb = (lane + k * 64) * 4;
        f4 s;
        s.x = (jb + 0 == t) ? (1.0f - SMOOTH) : (1.0f - e[k].x * inv_z) * coef;
        s.y = (jb + 1 == t) ? (1.0f - SMOOTH) : (1.0f - e[k].y * inv_z) * coef;
        s.z = (jb + 2 == t) ? (1.0f - SMOOTH) : (1.0f - e[k].z * inv_z) * coef;
        s.w = (jb + 3 == t) ? (1.0f - SMOOTH) : (1.0f - e[k].w * inv_z) * coef;
        Srt[lane + k * 64] = s;
        srow_l += (s.x + s.y) + (s.z + s.w);
    }
    if (lastl) {
        int jb = (lane + 192) * 4;
        f4 s;
        s.x = (jb + 0 == t) ? (1.0f - SMOOTH) : (1.0f - e[3].x * inv_z) * coef;
        s.y = (jb + 1 == t) ? (1.0f - SMOOTH) : (1.0f - e[3].y * inv_z) * coef;
        s.z = (jb + 2 == t) ? (1.0f - SMOOTH) : (1.0f - e[3].z * inv_z) * coef;
        s.w = (jb + 3 == t) ? (1.0f - SMOOTH) : (1.0f - e[3].w * inv_z) * coef;
        Srt[lane + 192] = s;
        srow_l += (s.x + s.y) + (s.z + s.w);
    }
    float srow = wave_reduce_sum(srow_l);
    if (lane == 0) Srow[t] = srow;
}

// ---------------- loss: class-grouped, S row register-resident ----------------
// Wave w handles class t = w/8, chunk c = w%8: samples order[offs[t]+c+8k].
// loss_b = log(Z_b)*Srow[t] - dot(S[t,:], x_b); no S gather, no tgt dependency.
__device__ inline void sample_zd(const f4* __restrict__ xr, int lane, bool lastl,
                                 const f4& s0, const f4& s1, const f4& s2,
                                 const f4& s3, float& z, float& d) {
    f4 x0 = NTLOAD(xr + lane);
    f4 x1 = NTLOAD(xr + lane + 64);
    f4 x2 = NTLOAD(xr + lane + 128);
    f4 x3 = lastl ? NTLOAD(xr + lane + 192)
                  : f4{-INFINITY, -INFINITY, -INFINITY, -INFINITY};
    z = __expf(x0.x) + __expf(x0.y) + __expf(x0.z) + __expf(x0.w)
      + __expf(x1.x) + __expf(x1.y) + __expf(x1.z) + __expf(x1.w)
      + __expf(x2.x) + __expf(x2.y) + __expf(x2.z) + __expf(x2.w)
      + __expf(x3.x) + __expf(x3.y) + __expf(x3.z) + __expf(x3.w);
    float dd = 0.f;
    dd = fmaf(s0.x, x0.x, dd); dd = fmaf(s0.y, x0.y, dd);
    dd = fmaf(s0.z, x0.z, dd); dd = fmaf(s0.w, x0.w, dd);
    dd = fmaf(s1.x, x1.x, dd); dd = fmaf(s1.y, x1.y, dd);
    dd = fmaf(s1.z, x1.z, dd); dd = fmaf(s1.w, x1.w, dd);
    dd = fmaf(s2.x, x2.x, dd); dd = fmaf(s2.y, x2.y, dd);
    dd = fmaf(s2.z, x2.z, dd); dd = fmaf(s2.w, x2.w, dd);
    f4 xf = lastl ? x3 : f4{0.f, 0.f, 0.f, 0.f};   // avoid 0 * -inf
    dd = fmaf(s3.x, xf.x, dd); dd = fmaf(s3.y, xf.y, dd);
    dd = fmaf(s3.z, xf.z, dd); dd = fmaf(s3.w, xf.w, dd);
    d = dd;
}

__global__ __launch_bounds__(256) void loss_kernel(
        const float* __restrict__ x, const float* __restrict__ S,
        const float* __restrict__ Srow, const int* __restrict__ offs,
        const int* __restrict__ order, float* __restrict__ partials) {
    int wave = threadIdx.x >> 6, lane = threadIdx.x & 63;
    int w = blockIdx.x * 4 + wave;               // 0..8191
    bool lastl = lane < (250 - 192);
    float lsum = 0.f;
    int t = w >> 3;
    if (t < C) {
        int c = w & 7;
        int o1 = offs[t + 1];
        int i = offs[t] + c;
        float ss = Srow[t];
        const f4* sr = (const f4*)(S + (size_t)t * C);
        f4 s0 = sr[lane];
        f4 s1 = sr[lane + 64];
        f4 s2 = sr[lane + 128];
        f4 s3 = lastl ? sr[lane + 192] : f4{0.f, 0.f, 0.f, 0.f};

        // two samples per iteration: loads for both issued before compute
        for (; i + WPC < o1; i += 2 * WPC) {
            int b0 = order[i];
            int b1 = order[i + WPC];
            const f4* xr0 = (const f4*)(x + (size_t)b0 * C);
            const f4* xr1 = (const f4*)(x + (size_t)b1 * C);
            float z0, d0, z1, d1;
            sample_zd(xr0, lane, lastl, s0, s1, s2, s3, z0, d0);
            sample_zd(xr1, lane, lastl, s0, s1, s2, s3, z1, d1);
            wave_reduce_sum4(z0, z1, d0, d1);
            lsum += (__logf(z0) + __logf(z1)) * ss - d0 - d1;
        }
        if (i < o1) {
            int b0 = order[i];
            const f4* xr0 = (const f4*)(x + (size_t)b0 * C);
            float z0, d0;
            sample_zd(xr0, lane, lastl, s0, s1, s2, s3, z0, d0);
            wave_reduce_sum2(z0, d0);
            lsum += __logf(z0) * ss - d0;
        }
    }
    if (lane == 0) partials[w] = lsum;
}

// ---------------- final reduce: 8192 partials -> mean ----------------
__global__ __launch_bounds__(256) void reduce_kernel(
        const float* __restrict__ partials, float* __restrict__ out) {
    __shared__ float sm[4];
    const f4* p4 = (const f4*)partials;     // 8192/4 = 2048 f4 = 256 thr * 8
    float s = 0.f;
    #pragma unroll
    for (int k = 0; k < 8; k++) {
        f4 v = p4[threadIdx.x + k * 256];
        s += (v.x + v.y) + (v.z + v.w);
    }
    s = block_reduce_sum(s, sm);
    if (threadIdx.x == 0) out[0] = s * (1.0f / (float)B);
}

extern "C" void kernel_launch(void* const* d_in, const int* in_sizes, int n_in,
                              void* d_out, int out_size, void* d_ws, size_t ws_size,
                              hipStream_t stream) {
    const float* x   = (const float*)d_in[0];
    const float* ca  = (const float*)d_in[1];
    const int*   tgt = (const int*)d_in[2];
    float* out = (float*)d_out;

    float* S        = (float*)d_ws;                  // 1,000,000 f (4 MB)
    float* Srow     = S + (size_t)C * C;             // 1000 f
    float* partials = Srow + C;                      // 8192 f
    int*   counts   = (int*)(partials + NWPAD);      // 1000 i
    int*   offs     = counts + C;                    // 1001 i
    int*   cursor   = offs + C + 1;                  // 1000 i
    int*   order    = cursor + C;                    // 65536 i

    smooth_kernel<<<C / 4, 256, 0, stream>>>(ca, S, Srow);
    zero_kernel<<<1, 256, 0, stream>>>(counts);
    hist_kernel<<<64, 256, 0, stream>>>(tgt, counts);
    prefix_kernel<<<1, 256, 0, stream>>>(counts, offs, cursor);
    scatter_kernel<<<64, 256, 0, stream>>>(tgt, cursor, order);
    loss_kernel<<<NWPAD / 4, 256, 0, stream>>>(x, S, Srow, offs, order, partials);
    reduce_kernel<<<1, 256, 0, stream>>>(partials, out);
}